// Round 8
// baseline (13257.024 us; speedup 1.0000x reference)
//
#include <hip/hip_runtime.h>
#include <math.h>
#include <stdint.h>

namespace {
constexpr int N_    = 2048;
constexpr int H_    = 800;
constexpr int IN_   = 28;
constexpr int TENC  = 28;
constexpr int TTOT  = 78;             // 28 encode + 50 decode
constexpr int ONUM  = 10;
constexpr int SPB   = 32;             // samples per block
constexpr int NBLK  = N_ / SPB;       // 64 persistent blocks, zero inter-block comms
constexpr int NT    = 50;             // hidden 16-neuron N-tiles
constexpr int KT    = 13;             // K-tiles: 800 -> 832 (tile 12 half zero-pad)
constexpr int AROW  = 27;             // spike row stride (dwords): 26 data + 1 pad
// dynamic LDS layout (dword offsets)
constexpr int L_WI  = 0;                     // wiL [28][800] f32
constexpr int L_SP0 = IN_ * H_;              // 22400: spk buf0 [32][27] u32
constexpr int L_SP1 = L_SP0 + SPB * AROW;    // 23264: spk buf1
constexpr int L_XS0 = L_SP1 + SPB * AROW;    // 24128: xs buf0 [28][32] f32
constexpr int L_XS1 = L_XS0 + IN_ * SPB;     // 25024: xs buf1
constexpr int L_TOT = L_XS1 + IN_ * SPB;     // 25920 dwords = 103680 B -> 1 blk/CU
}

typedef __attribute__((ext_vector_type(4))) int v4i;

// balanced base-256 digits of round(w * 2^32); exact for |w| < ~0.49
__device__ __forceinline__ void digitize(float w, int8_t d[4]) {
    double dd = (double)w * 4294967296.0;
    long long r = (long long)rint(dd);
    int8_t d0 = (int8_t)(r & 255); r = (r - (long long)d0) >> 8;
    int8_t d1 = (int8_t)(r & 255); r = (r - (long long)d1) >> 8;
    int8_t d2 = (int8_t)(r & 255); r = (r - (long long)d2) >> 8;
    long long r3 = r; r3 = r3 > 127 ? 127 : (r3 < -128 ? -128 : r3);
    d[0] = d0; d[1] = d1; d[2] = d2; d[3] = (int8_t)r3;
}

// expand 16 spike bits -> 16 bytes (0/1) as v4i
__device__ __forceinline__ v4i unpack16(uint32_t u) {
    v4i f;
    f[0] = (int)((((u      ) & 0xFu) * 0x00204081u) & 0x01010101u);
    f[1] = (int)((((u >>  4) & 0xFu) * 0x00204081u) & 0x01010101u);
    f[2] = (int)((((u >>  8) & 0xFu) * 0x00204081u) & 0x01010101u);
    f[3] = (int)((((u >> 12) & 0xFu) * 0x00204081u) & 0x01010101u);
    return f;
}

// ---------------------------------------------------------------------------
// prepass: (1) transpose x into xt2[t][n][c]; (2) digitize Wh/Wo into global
// MFMA B-fragment layout Bdig[nt][c][plane][lane][16B] (identical math to the
// previously-passing in-LDS builder; layout byte-compatible with consumption).
// ---------------------------------------------------------------------------
__global__ void prep_kernel(const float* __restrict__ x,
                            const float* __restrict__ Wh,
                            const float* __restrict__ Wo,
                            float* __restrict__ xt2,
                            int8_t* __restrict__ Bdig,
                            int8_t* __restrict__ Bodig)
{
    size_t idx = (size_t)blockIdx.x * blockDim.x + threadIdx.x;
    size_t stride = (size_t)gridDim.x * blockDim.x;
    const size_t TOT = (size_t)TENC * N_ * IN_;
    for (size_t e = idx; e < TOT; e += stride) {
        int t = (int)(e / (N_ * IN_));
        int rem = (int)(e % (N_ * IN_));
        int n = rem / IN_, c = rem % IN_;
        xt2[e] = x[(size_t)n * 784 + c * TENC + t];
    }
    // hidden weights: 50 tiles x 13 k-tiles x 64 lanes
    for (size_t e = idx; e < (size_t)NT * KT * 64; e += stride) {
        int nt  = (int)(e / (KT * 64));
        int rem = (int)(e % (KT * 64));
        int c = rem >> 6, ln = rem & 63;
        int q = ln >> 4, cl = ln & 15;
        int neuron = nt * 16 + cl;
        uint32_t w4[4][4] = {};
        #pragma unroll
        for (int j = 0; j < 16; ++j) {
            int kidx = c * 64 + q * 16 + j;
            float w = (kidx < H_) ? Wh[(size_t)neuron * H_ + kidx] : 0.f;
            int8_t d[4]; digitize(w, d);
            #pragma unroll
            for (int pl = 0; pl < 4; ++pl)
                w4[pl][j >> 2] |= ((uint32_t)(uint8_t)d[pl]) << ((j & 3) * 8);
        }
        #pragma unroll
        for (int pl = 0; pl < 4; ++pl) {
            v4i v; v[0] = (int)w4[pl][0]; v[1] = (int)w4[pl][1];
            v[2] = (int)w4[pl][2]; v[3] = (int)w4[pl][3];
            *(v4i*)(Bdig + (((size_t)(nt * KT + c) * 4 + pl) << 10) + (ln << 4)) = v;
        }
    }
    // output weights: 1 tile (cols 0..9 real) x 13 k-tiles
    for (size_t e = idx; e < (size_t)KT * 64; e += stride) {
        int c = (int)(e >> 6), ln = (int)(e & 63);
        int q = ln >> 4, cl = ln & 15;
        uint32_t w4[4][4] = {};
        #pragma unroll
        for (int j = 0; j < 16; ++j) {
            int kidx = c * 64 + q * 16 + j;
            float w = (cl < ONUM && kidx < H_) ? Wo[(size_t)cl * H_ + kidx] : 0.f;
            int8_t d[4]; digitize(w, d);
            #pragma unroll
            for (int pl = 0; pl < 4; ++pl)
                w4[pl][j >> 2] |= ((uint32_t)(uint8_t)d[pl]) << ((j & 3) * 8);
        }
        #pragma unroll
        for (int pl = 0; pl < 4; ++pl) {
            v4i v; v[0] = (int)w4[pl][0]; v[1] = (int)w4[pl][1];
            v[2] = (int)w4[pl][2]; v[3] = (int)w4[pl][3];
            *(v4i*)(Bodig + (((size_t)c * 4 + pl) << 10) + (ln << 4)) = v;
        }
    }
}

// ---------------------------------------------------------------------------
// Persistent block-local LSNN: 64 blocks x 32 samples; each block runs ALL
// 800 hidden + 10 output neurons for its samples. Recurrence state (spike
// bits, membrane, adaptation) never leaves the CU: spikes in LDS (double-
// buffered bit rows), hm/hb in registers. One __syncthreads per step; NO
// global spike exchange, NO flags, NO agent-scope ops.
// Weights stream from XCD L2 (Bdig is a single shared 2.66MB read-only copy,
// L2-resident). Input projection (fp64 exact, same order cp=0..27 as the
// passing kernel) is interleaved into the MFMA k-loop to hide L2 latency.
// Tile->wave map: nt (0..49) -> wave nt&7; waves 0,1 own 7 tiles, 2..7 own 6;
// wave 7 additionally computes the output layer (step t-1 at iter t).
// ---------------------------------------------------------------------------
__global__ __launch_bounds__(512)
__attribute__((amdgpu_waves_per_eu(2)))
void lsnn_local(const float* __restrict__ xt2,
                const int8_t* __restrict__ Bdig,
                const int8_t* __restrict__ Bodig,
                const float* __restrict__ Wi,
                const float* __restrict__ b_i2h,
                const float* __restrict__ b_h2h,
                const float* __restrict__ b_h2o,
                const float* __restrict__ tau_h,
                const float* __restrict__ tau_o,
                float* __restrict__ out)
{
    extern __shared__ __align__(16) uint32_t sm[];
    float* wiL = (float*)(sm + L_WI);     // [28][800]

    const int n0s  = blockIdx.x * SPB;
    const int wv   = threadIdx.x >> 6;
    const int lane = threadIdx.x & 63;
    const int quad = lane >> 4;
    const int col  = lane & 15;
    const int dsel = (quad >> 1);
    const int dsh  = (quad & 1) * 16;
    const int myT  = (wv < 2) ? 7 : 6;
    const bool is_ow = (wv == 7);
    const v4i* Bv  = (const v4i*)Bdig;
    const v4i* Bov = (const v4i*)Bodig;

    // ---- LDS init: Wi tile, zero spike buffers, xs for t=0 ----
    for (int e = threadIdx.x; e < IN_ * H_; e += 512) {
        int c = e / H_, n = e % H_;
        wiL[e] = Wi[(size_t)n * IN_ + c];
    }
    for (int e = threadIdx.x; e < 2 * SPB * AROW; e += 512) sm[L_SP0 + e] = 0u;
    for (int e = threadIdx.x; e < IN_ * SPB; e += 512) {
        int c = e >> 5, s = e & 31;
        ((float*)(sm + L_XS0))[c * SPB + s] = xt2[((size_t)0 * N_ + n0s + s) * IN_ + c];
    }

    // ---- constants & register state ----
    const float alpha = (float)exp((double)(-1.0f / 20.0f));
    const float onem  = 1.0f - alpha;
    const double INV32 = 1.0 / 4294967296.0;

    float roB[7], biB[7], bhB[7];
    float hm[7][2][4] = {}, hb[7][2][4];
    #pragma unroll
    for (int j = 0; j < 7; ++j) {
        roB[j] = 0.f; biB[j] = 0.f; bhB[j] = 0.f;
        if (j < myT) {
            int neuron = (wv + 8 * j) * 16 + col;
            float arg = -1.0f / tau_h[neuron];
            roB[j] = (float)exp((double)arg);
            biB[j] = b_i2h[neuron]; bhB[j] = b_h2h[neuron];
        }
        #pragma unroll
        for (int a = 0; a < 2; ++a)
            #pragma unroll
            for (int r = 0; r < 4; ++r) hb[j][a][r] = 0.01f;
    }
    uint64_t pmask = 0ull;

    float om[2][4] = {}, ospv[2][4] = {}, obb[2][4], cnt[2][4] = {};
    float roO = 0.f, boO = 0.f;
    if (is_ow && col < ONUM) {
        float arg = -1.0f / tau_o[col];
        roO = (float)exp((double)arg);
        boO = b_h2o[col];
    }
    #pragma unroll
    for (int a = 0; a < 2; ++a)
        #pragma unroll
        for (int r = 0; r < 4; ++r) obb[a][r] = 0.01f;

    __syncthreads();

    // ---- time loop: ONE intra-block barrier per iteration ----
    for (int t = 0; t <= TTOT; ++t) {
        const uint32_t* spkC = sm + ((t & 1) ? L_SP1 : L_SP0);
        uint32_t*       spkN = sm + ((t & 1) ? L_SP0 : L_SP1);
        const float*    xsC  = (const float*)(sm + ((t & 1) ? L_XS1 : L_XS0));

        // ---- output layer (wave 7): reference step t-1 from spkC ----
        if (is_ow && t >= 1) {
            v4i oacc[2][4] = {};
            #pragma unroll
            for (int c = 0; c < KT; ++c) {
                const v4i b0 = Bov[(c * 4 + 0) * 64 + lane];
                const v4i b1 = Bov[(c * 4 + 1) * 64 + lane];
                const v4i b2 = Bov[(c * 4 + 2) * 64 + lane];
                const v4i b3 = Bov[(c * 4 + 3) * 64 + lane];
                const uint32_t d0 = spkC[col * AROW + 2 * c + dsel];
                const uint32_t d1 = spkC[(16 + col) * AROW + 2 * c + dsel];
                const v4i a0 = unpack16((d0 >> dsh) & 0xFFFFu);
                const v4i a1 = unpack16((d1 >> dsh) & 0xFFFFu);
                oacc[0][0] = __builtin_amdgcn_mfma_i32_16x16x64_i8(a0, b0, oacc[0][0], 0, 0, 0);
                oacc[0][1] = __builtin_amdgcn_mfma_i32_16x16x64_i8(a0, b1, oacc[0][1], 0, 0, 0);
                oacc[0][2] = __builtin_amdgcn_mfma_i32_16x16x64_i8(a0, b2, oacc[0][2], 0, 0, 0);
                oacc[0][3] = __builtin_amdgcn_mfma_i32_16x16x64_i8(a0, b3, oacc[0][3], 0, 0, 0);
                oacc[1][0] = __builtin_amdgcn_mfma_i32_16x16x64_i8(a1, b0, oacc[1][0], 0, 0, 0);
                oacc[1][1] = __builtin_amdgcn_mfma_i32_16x16x64_i8(a1, b1, oacc[1][1], 0, 0, 0);
                oacc[1][2] = __builtin_amdgcn_mfma_i32_16x16x64_i8(a1, b2, oacc[1][2], 0, 0, 0);
                oacc[1][3] = __builtin_amdgcn_mfma_i32_16x16x64_i8(a1, b3, oacc[1][3], 0, 0, 0);
            }
            if (col < ONUM) {
                #pragma clang fp contract(off)
                const bool msk = (t - 1) >= TENC;
                #pragma unroll
                for (int a = 0; a < 2; ++a) {
                    #pragma unroll
                    for (int r = 0; r < 4; ++r) {
                        int64_t tot = ((int64_t)oacc[a][3][r] << 24)
                                    + ((int64_t)oacc[a][2][r] << 16)
                                    + ((int64_t)oacc[a][1][r] << 8)
                                    +  (int64_t)oacc[a][0][r];
                        float o_in = ((float)((double)tot * INV32)) + boO;
                        float osp_ = ospv[a][r];
                        float bnew = (roO * obb[a][r]) + ((1.0f - roO) * osp_);
                        float B = 0.01f + (1.8f * bnew);
                        float mem = ((om[a][r] * alpha) + (onem * o_in)) - (B * osp_);
                        float s = (mem - B) > 0.f ? 1.f : 0.f;
                        obb[a][r] = bnew; om[a][r] = mem; ospv[a][r] = s;
                        if (msk) cnt[a][r] += s;
                    }
                }
            }
        }

        // ---- hidden layer: step t (all waves, their N-tiles) ----
        if (t < TTOT) {
            const bool enc = (t < TENC);
            #pragma unroll
            for (int j = 0; j < 7; ++j) {
                if (j < myT) {
                    const int nt = wv + 8 * j;
                    const int ncol = nt * 16 + col;
                    const v4i* Bp = Bv + (size_t)(nt * KT * 4) * 64 + lane;
                    v4i ac0[4] = {}, ac1[4] = {};
                    double inj[2][4] = {};
                    #pragma unroll
                    for (int c = 0; c < KT; ++c) {
                        const v4i b0 = Bp[(c * 4 + 0) * 64];
                        const v4i b1 = Bp[(c * 4 + 1) * 64];
                        const v4i b2 = Bp[(c * 4 + 2) * 64];
                        const v4i b3 = Bp[(c * 4 + 3) * 64];
                        const uint32_t d0 = spkC[col * AROW + 2 * c + dsel];
                        const uint32_t d1 = spkC[(16 + col) * AROW + 2 * c + dsel];
                        const v4i a0 = unpack16((d0 >> dsh) & 0xFFFFu);
                        const v4i a1 = unpack16((d1 >> dsh) & 0xFFFFu);
                        ac0[0] = __builtin_amdgcn_mfma_i32_16x16x64_i8(a0, b0, ac0[0], 0, 0, 0);
                        ac0[1] = __builtin_amdgcn_mfma_i32_16x16x64_i8(a0, b1, ac0[1], 0, 0, 0);
                        ac0[2] = __builtin_amdgcn_mfma_i32_16x16x64_i8(a0, b2, ac0[2], 0, 0, 0);
                        ac0[3] = __builtin_amdgcn_mfma_i32_16x16x64_i8(a0, b3, ac0[3], 0, 0, 0);
                        ac1[0] = __builtin_amdgcn_mfma_i32_16x16x64_i8(a1, b0, ac1[0], 0, 0, 0);
                        ac1[1] = __builtin_amdgcn_mfma_i32_16x16x64_i8(a1, b1, ac1[1], 0, 0, 0);
                        ac1[2] = __builtin_amdgcn_mfma_i32_16x16x64_i8(a1, b2, ac1[2], 0, 0, 0);
                        ac1[3] = __builtin_amdgcn_mfma_i32_16x16x64_i8(a1, b3, ac1[3], 0, 0, 0);
                        // interleaved exact input projection (encode steps):
                        // fp64, cp ascending 0..27 -> same order as passing kernel
                        if (enc) {
                            #pragma unroll
                            for (int u = 0; u < ((c == 12) ? 4 : 2); ++u) {
                                const int cp = 2 * c + u;
                                const double wd = (double)wiL[cp * H_ + ncol];
                                const float4 xa = *(const float4*)(xsC + cp * SPB + quad * 4);
                                const float4 xb = *(const float4*)(xsC + cp * SPB + 16 + quad * 4);
                                inj[0][0] += (double)xa.x * wd;
                                inj[0][1] += (double)xa.y * wd;
                                inj[0][2] += (double)xa.z * wd;
                                inj[0][3] += (double)xa.w * wd;
                                inj[1][0] += (double)xb.x * wd;
                                inj[1][1] += (double)xb.y * wd;
                                inj[1][2] += (double)xb.z * wd;
                                inj[1][3] += (double)xb.w * wd;
                            }
                        }
                    }
                    // epilogue: fp32, reference order, no FMA
                    uint32_t sb = 0;
                    {
                        #pragma clang fp contract(off)
                        #pragma unroll
                        for (int a = 0; a < 2; ++a) {
                            #pragma unroll
                            for (int r = 0; r < 4; ++r) {
                                const v4i* acp = a ? ac1 : ac0;
                                int64_t tot = ((int64_t)acp[3][r] << 24)
                                            + ((int64_t)acp[2][r] << 16)
                                            + ((int64_t)acp[1][r] << 8)
                                            +  (int64_t)acp[0][r];
                                float rec = (float)((double)tot * INV32);
                                float inpf = enc ? (float)inj[a][r] : 0.0f;
                                float h_in = ((inpf + biB[j]) + rec) + bhB[j];
                                float sp = ((pmask >> (j * 8 + a * 4 + r)) & 1ull) ? 1.0f : 0.0f;
                                float ro = roB[j];
                                float bnew = (ro * hb[j][a][r]) + ((1.0f - ro) * sp);
                                float B = 0.01f + (1.8f * bnew);
                                float mem = ((hm[j][a][r] * alpha) + (onem * h_in)) - (B * sp);
                                float s = (mem - B) > 0.f ? 1.f : 0.f;
                                hb[j][a][r] = bnew; hm[j][a][r] = mem;
                                if (s > 0.5f) sb |= 1u << (a * 4 + r);
                            }
                        }
                    }
                    pmask = (pmask & ~(0xFFull << (j * 8))) | ((uint64_t)sb << (j * 8));
                    // pack: ballots -> halfword nt of each sample row in spkN
                    #pragma unroll
                    for (int a = 0; a < 2; ++a) {
                        #pragma unroll
                        for (int r = 0; r < 4; ++r) {
                            unsigned long long bal = __ballot((sb >> (a * 4 + r)) & 1u);
                            if (col == a * 4 + r) {
                                uint16_t hw = (uint16_t)((bal >> (quad * 16)) & 0xFFFFull);
                                int sample = a * 16 + quad * 4 + r;
                                ((uint16_t*)spkN)[sample * (AROW * 2) + nt] = hw;
                            }
                        }
                    }
                }
            }
            // prefetch next encode-step inputs into the other xs buffer
            if (t + 1 < TENC) {
                float* xsN = (float*)(sm + ((t & 1) ? L_XS0 : L_XS1));
                for (int e = threadIdx.x; e < IN_ * SPB; e += 512) {
                    int c = e >> 5, s = e & 31;
                    xsN[c * SPB + s] = xt2[((size_t)(t + 1) * N_ + n0s + s) * IN_ + c];
                }
            }
        }

        __syncthreads();
    }

    // ---- write spike counts ----
    if (is_ow && col < ONUM) {
        #pragma unroll
        for (int a = 0; a < 2; ++a)
            #pragma unroll
            for (int r = 0; r < 4; ++r) {
                int n = n0s + a * 16 + quad * 4 + r;
                out[(size_t)n * ONUM + col] = cnt[a][r];
            }
    }
}

// ---------------------------------------------------------------------------
extern "C" void kernel_launch(void* const* d_in, const int* in_sizes, int n_in,
                              void* d_out, int out_size, void* d_ws, size_t ws_size,
                              hipStream_t stream)
{
    const float* x      = (const float*)d_in[0];
    const float* Wi     = (const float*)d_in[1];
    const float* b_i2h  = (const float*)d_in[2];
    const float* Wh     = (const float*)d_in[3];
    const float* b_h2h  = (const float*)d_in[4];
    const float* Wo     = (const float*)d_in[5];
    const float* b_h2o  = (const float*)d_in[6];
    const float* tau_h  = (const float*)d_in[7];
    const float* tau_o  = (const float*)d_in[8];
    float* out = (float*)d_out;

    uintptr_t p = (uintptr_t)d_ws;
    auto alloc = [&](size_t bytes) -> void* {
        p = (p + 255) & ~(uintptr_t)255;
        void* r = (void*)p; p += bytes; return r;
    };
    float*  xt2   = (float*)alloc((size_t)TENC * N_ * IN_ * 4);     // 6.42 MB
    int8_t* Bdig  = (int8_t*)alloc((size_t)NT * KT * 4 * 1024);     // 2.66 MB
    int8_t* Bodig = (int8_t*)alloc((size_t)KT * 4 * 1024);          // 53 KB

    prep_kernel<<<1024, 256, 0, stream>>>(x, Wh, Wo, xt2, Bdig, Bodig);

    (void)hipFuncSetAttribute((const void*)lsnn_local,
                              hipFuncAttributeMaxDynamicSharedMemorySize, L_TOT * 4);
    lsnn_local<<<NBLK, 512, L_TOT * 4, stream>>>(
        xt2, Bdig, Bodig, Wi, b_i2h, b_h2h, b_h2o, tau_h, tau_o, out);
}

// Round 10
// 1382.585 us; speedup vs baseline: 9.5886x; 9.5886x over previous
//
#include <hip/hip_runtime.h>
#include <math.h>
#include <stdint.h>

namespace {
constexpr int N_    = 2048;
constexpr int H_    = 800;
constexpr int IN_   = 28;
constexpr int TENC  = 28;
constexpr int TTOT  = 78;             // 28 encode + 50 decode
constexpr int ONUM  = 10;
constexpr int PODS  = 8;              // independent 256-sample pods
constexpr int PBLK  = 26;             // 25 hidden tiles + 1 output block per pod
constexpr int NBLK  = PODS * PBLK;    // 208
constexpr int NTILE = 26;             // spike strips: 25 real tiles + 1 zero K-pad
constexpr int FSTR  = 32;             // flag dwords per pod (26 used -> 2 lines)
constexpr int NSEG  = 13 * 4 * 2;     // (c, digit k, neuron-half) B segments
constexpr int SMEM_B = NSEG * 1024;          // 106496: fragment-ordered digit planes
constexpr int SMEM_W = IN_ * 32 * 4;         // 3584: Wi tile
constexpr int AROW  = 27;                    // LDS A-strip row stride (dwords)
constexpr int SMEM_A = 8 * 32 * AROW * 4;    // 27648: per-wave A strips
constexpr int SMEM_TOT = SMEM_B + SMEM_W + SMEM_A;  // 137728 <= 160K -> 1 blk/CU
}

typedef __attribute__((ext_vector_type(4))) int v4i;

// balanced base-256 digits of round(w * 2^32); exact for |w| < ~0.49
__device__ __forceinline__ void digitize(float w, int8_t d[4]) {
    double dd = (double)w * 4294967296.0;
    long long r = (long long)rint(dd);
    int8_t d0 = (int8_t)(r & 255); r = (r - (long long)d0) >> 8;
    int8_t d1 = (int8_t)(r & 255); r = (r - (long long)d1) >> 8;
    int8_t d2 = (int8_t)(r & 255); r = (r - (long long)d2) >> 8;
    long long r3 = r; r3 = r3 > 127 ? 127 : (r3 < -128 ? -128 : r3);
    d[0] = d0; d[1] = d1; d[2] = d2; d[3] = (int8_t)r3;
}

// expand 16 spike bits -> 16 bytes (0/1) as v4i
__device__ __forceinline__ v4i unpack16(uint32_t u) {
    v4i f;
    f[0] = (int)((((u      ) & 0xFu) * 0x00204081u) & 0x01010101u);
    f[1] = (int)((((u >>  4) & 0xFu) * 0x00204081u) & 0x01010101u);
    f[2] = (int)((((u >>  8) & 0xFu) * 0x00204081u) & 0x01010101u);
    f[3] = (int)((((u >> 12) & 0xFu) * 0x00204081u) & 0x01010101u);
    return f;
}

// ---- pod-local grid barrier: 26 blocks, packed flag lines (2/pod) ---------
// Backoff after 4 iterations cuts MALL poll congestion during the staging
// burst; s_sleep args are CONSTANT literals (builtin requirement).
__device__ __forceinline__ void pod_barrier(uint32_t* __restrict__ flags,
                                            int pod, int l, uint32_t epoch) {
    __syncthreads();
    if (threadIdx.x < 64) {
        if (threadIdx.x == 0) {
            asm volatile("s_waitcnt vmcnt(0)" ::: "memory");
            __hip_atomic_store(flags + pod * FSTR + l, epoch,
                               __ATOMIC_RELAXED, __HIP_MEMORY_SCOPE_AGENT);
        }
        const bool mine = (threadIdx.x < PBLK);
        bool done = false;
        int itc = 0;
        while (!done) {
            bool ok = true;
            if (mine)
                ok = (__hip_atomic_load(flags + pod * FSTR + threadIdx.x,
                        __ATOMIC_RELAXED, __HIP_MEMORY_SCOPE_AGENT) >= epoch);
            done = (__ballot(ok) == ~0ull);
            if (!done) {
                if (itc < 4) __builtin_amdgcn_s_sleep(1);
                else         __builtin_amdgcn_s_sleep(8);
                ++itc;
            }
        }
    }
    __syncthreads();
}

// ---------------------------------------------------------------------------
// prepass: transpose x into xt2[t][n][c], zero tile-major spike buffers+flags
// ---------------------------------------------------------------------------
__global__ void prep_kernel(const float* __restrict__ x, float* __restrict__ xt2,
                            uint32_t* __restrict__ sp0, uint32_t* __restrict__ sp1,
                            uint32_t* __restrict__ flags)
{
    size_t idx = (size_t)blockIdx.x * blockDim.x + threadIdx.x;
    size_t stride = (size_t)gridDim.x * blockDim.x;
    const size_t TOT = (size_t)TENC * N_ * IN_;
    for (size_t e = idx; e < TOT; e += stride) {
        int t = (int)(e / (N_ * IN_));
        int rem = (int)(e % (N_ * IN_));
        int n = rem / IN_, c = rem % IN_;
        xt2[e] = x[(size_t)n * 784 + c * TENC + t];
    }
    const size_t PW = (size_t)NTILE * N_;
    for (size_t e = idx; e < PW; e += stride) { sp0[e] = 0u; sp1[e] = 0u; }
    for (size_t e = idx; e < (size_t)PODS * FSTR; e += stride) flags[e] = 0u;
}

// ---------------------------------------------------------------------------
// Persistent LSNN, pod-local sync, TILE-MAJOR spike exchange (round-6 base):
//   sp[strip][n], strips 0..24 real; strip 25 never loaded (LDS K-pad cells
//   zeroed once). Staging: issue 13 reg loads -> overlap fp64 input proj ->
//   LDS writes. Spike stores: 16 lanes x 8B atomic qwords (one contiguous
//   128B segment/wave; half the fabric transactions of 32x4B).
// ---------------------------------------------------------------------------
__global__ __launch_bounds__(512)
__attribute__((amdgpu_waves_per_eu(2)))
void lsnn_persist(const float* __restrict__ xt2,
                  const float* __restrict__ Wi,
                  const float* __restrict__ b_i2h,
                  const float* __restrict__ Wh,
                  const float* __restrict__ b_h2h,
                  const float* __restrict__ Wo,
                  const float* __restrict__ b_h2o,
                  const float* __restrict__ tau_h,
                  const float* __restrict__ tau_o,
                  uint32_t* sp0, uint32_t* sp1,
                  uint32_t* flags,
                  float* __restrict__ out)
{
    extern __shared__ __align__(16) int8_t smem[];
    int8_t*   Bl  = smem;                                   // [NSEG][64][16]
    float*    wl  = (float*)(smem + SMEM_B);                // [28][32]
    uint32_t* Alds = (uint32_t*)(smem + SMEM_B + SMEM_W);   // [8 waves][32][AROW]

    const int bid  = blockIdx.x;
    const int pod  = bid / PBLK;          // 0..7 (sample group)
    const int l    = bid % PBLK;          // 0..25 (25 = o-block)
    const bool is_o = (l == 25);
    const int it   = is_o ? 0 : l;
    const int i0   = it * 32;
    const int wv   = threadIdx.x >> 6;
    const int lane = threadIdx.x & 63;
    const int quad = lane >> 4;
    const int col  = lane & 15;
    const int n0   = pod * 256 + wv * 32;
    uint32_t* ldsA = Alds + wv * 32 * AROW;
    const int dsel = (quad >> 1);
    const int dsh  = (quad & 1) * 16;

    // ---- build B digit fragments in LDS (once) ----
    for (int e = threadIdx.x; e < 13 * 2 * 64; e += 512) {
        int c  = e >> 7;
        int bh = (e >> 6) & 1;
        int ln = e & 63;
        int q  = ln >> 4, cl = ln & 15;
        int kbase = c * 64 + q * 16;
        uint32_t w4[4][4] = {};
        int row = bh * 16 + cl;
        #pragma unroll
        for (int j = 0; j < 16; ++j) {
            int kidx = kbase + j;
            float w = 0.f;
            if (kidx < H_) {
                if (!is_o) w = Wh[(size_t)(i0 + row) * H_ + kidx];
                else if (bh == 0 && cl < ONUM) w = Wo[(size_t)cl * H_ + kidx];
            }
            int8_t d[4]; digitize(w, d);
            #pragma unroll
            for (int k = 0; k < 4; ++k)
                w4[k][j >> 2] |= ((uint32_t)(uint8_t)d[k]) << ((j & 3) * 8);
        }
        #pragma unroll
        for (int k = 0; k < 4; ++k) {
            v4i v; v[0] = (int)w4[k][0]; v[1] = (int)w4[k][1];
            v[2] = (int)w4[k][2]; v[3] = (int)w4[k][3];
            *(v4i*)(Bl + (((c * 8) + k * 2 + bh) << 10) + (ln << 4)) = v;
        }
    }
    if (!is_o) {
        for (int e = threadIdx.x; e < IN_ * 32; e += 512) {
            int c = e >> 5, il = e & 31;
            wl[c * 32 + il] = Wi[(size_t)(i0 + il) * IN_ + c];
        }
    }
    // zero this wave's permanent K-pad column (strip 25 cells), written nowhere else
    if (lane >= 32) ldsA[(lane & 31) * AROW + 25] = 0u;

    // ---- constants & register state ----
    const float alpha = (float)exp((double)(-1.0f / 20.0f));
    const float onem  = 1.0f - alpha;
    const double INV32 = 1.0 / 4294967296.0;

    float roB[2] = {}, biB[2] = {}, bhB[2] = {};
    float hm[2][2][4] = {}, hbv[2][2][4];
    float om[2][4] = {}, ospv[2][4] = {}, obb[2][4], cnt[2][4] = {};
    float roO = 0.f, boO = 0.f;
    uint32_t pmask = 0;   // prev spikes for this lane's 16 outputs

    if (!is_o) {
        #pragma unroll
        for (int b = 0; b < 2; ++b) {
            int i = i0 + b * 16 + col;
            float arg = -1.0f / tau_h[i];
            roB[b] = (float)exp((double)arg);
            biB[b] = b_i2h[i]; bhB[b] = b_h2h[i];
        }
        #pragma unroll
        for (int a = 0; a < 2; ++a)
            #pragma unroll
            for (int b = 0; b < 2; ++b)
                #pragma unroll
                for (int r = 0; r < 4; ++r) hbv[a][b][r] = 0.01f;
    } else {
        if (col < ONUM) {
            float arg = -1.0f / tau_o[col];
            roO = (float)exp((double)arg);
            boO = b_h2o[col];
        }
        #pragma unroll
        for (int a = 0; a < 2; ++a)
            #pragma unroll
            for (int r = 0; r < 4; ++r) obb[a][r] = 0.01f;
    }

    // ---- per-lane staging geometry (constant across time) ----
    // load k: strip 2k + (lane>>5), row n0 + (lane&31); k=12 only lanes<32
    // (strip 25 is the permanent zero pad -> never loaded).
    uint32_t goff[13]; int loffv[13];
    #pragma unroll
    for (int k = 0; k < 13; ++k) {
        int tile = 2 * k + (lane >> 5);
        goff[k]  = (uint32_t)(tile * N_ + n0 + (lane & 31));
        loffv[k] = (lane & 31) * AROW + tile;
    }
    // qword spike-store gather: lane p<16 stores rows 2p,2p+1.
    // word for row j is held by lane ((j>>2)&3)*16 + ((j>>4)<<2) + (j&3).
    const int j0 = (lane & 15) * 2;
    const int j1 = j0 + 1;
    const int s0 = ((j0 >> 2) & 3) * 16 + ((j0 >> 4) << 2) + (j0 & 3);
    const int s1 = ((j1 >> 2) & 3) * 16 + ((j1 >> 4) << 2) + (j1 & 3);

    __syncthreads();
    uint32_t epoch = 1;

    // ---- time loop ----
    for (int t = 0; t <= TTOT; ++t) {
        const uint32_t* rdP = (t & 1) ? sp1 : sp0;
        uint32_t*       wrP = (t & 1) ? sp0 : sp1;

        const bool active = is_o ? (t >= 1) : (t < TTOT);

        // ---- issue staged loads into registers (latency overlapped below) ----
        uint32_t vv[13];
        if (active) {
            #pragma unroll
            for (int k = 0; k < 13; ++k) {
                const bool real = (k < 12) || (lane < 32);
                vv[k] = real ? __hip_atomic_load(rdP + goff[k],
                            __ATOMIC_RELAXED, __HIP_MEMORY_SCOPE_AGENT) : 0u;
            }
        }

        // ---- input projection (spike-independent): overlaps load latency ----
        float inpf[2][2][4] = {};
        if (!is_o && active && t < TENC) {
            #pragma unroll
            for (int a = 0; a < 2; ++a) {
                #pragma unroll
                for (int r = 0; r < 4; ++r) {
                    int n = n0 + a * 16 + quad * 4 + r;
                    const float* xp = xt2 + ((size_t)t * N_ + n) * IN_;
                    double s0d = 0.0, s1d = 0.0;
                    #pragma unroll
                    for (int c = 0; c < IN_; ++c) {
                        double xv = (double)xp[c];
                        s0d += xv * (double)wl[c * 32 + col];
                        s1d += xv * (double)wl[c * 32 + 16 + col];
                    }
                    inpf[a][0][r] = (float)s0d;
                    inpf[a][1][r] = (float)s1d;
                }
            }
        }

        // ---- land staged words in this wave's A strip ----
        if (active) {
            #pragma unroll
            for (int k = 0; k < 13; ++k) {
                const bool real = (k < 12) || (lane < 32);
                if (real) ldsA[loffv[k]] = vv[k];
            }
        }

        if (!is_o && active) {
            v4i acc4[2][2][4] = {};
            #pragma unroll
            for (int c = 0; c < 13; ++c) {
                uint32_t d0 = ldsA[col * AROW + c * 2 + dsel];
                uint32_t d1 = ldsA[(16 + col) * AROW + c * 2 + dsel];
                v4i a0 = unpack16((d0 >> dsh) & 0xFFFFu);
                v4i a1 = unpack16((d1 >> dsh) & 0xFFFFu);
                #pragma unroll
                for (int k = 0; k < 4; ++k) {
                    v4i b0 = *(const v4i*)(Bl + (((c * 8) + k * 2 + 0) << 10) + (lane << 4));
                    v4i b1 = *(const v4i*)(Bl + (((c * 8) + k * 2 + 1) << 10) + (lane << 4));
                    acc4[0][0][k] = __builtin_amdgcn_mfma_i32_16x16x64_i8(a0, b0, acc4[0][0][k], 0, 0, 0);
                    acc4[0][1][k] = __builtin_amdgcn_mfma_i32_16x16x64_i8(a0, b1, acc4[0][1][k], 0, 0, 0);
                    acc4[1][0][k] = __builtin_amdgcn_mfma_i32_16x16x64_i8(a1, b0, acc4[1][0][k], 0, 0, 0);
                    acc4[1][1][k] = __builtin_amdgcn_mfma_i32_16x16x64_i8(a1, b1, acc4[1][1][k], 0, 0, 0);
                }
            }

            // hidden epilogue: fp32, reference order, no FMA; state in registers
            uint32_t nmask = 0;
            {
                #pragma clang fp contract(off)
                #pragma unroll
                for (int a = 0; a < 2; ++a) {
                    #pragma unroll
                    for (int b = 0; b < 2; ++b) {
                        #pragma unroll
                        for (int r = 0; r < 4; ++r) {
                            int sidx = ((a * 2 + b) * 4 + r);
                            int64_t tot = ((int64_t)acc4[a][b][3][r] << 24)
                                        + ((int64_t)acc4[a][b][2][r] << 16)
                                        + ((int64_t)acc4[a][b][1][r] << 8)
                                        +  (int64_t)acc4[a][b][0][r];
                            float rec = (float)((double)tot * INV32);
                            float h_in = ((inpf[a][b][r] + biB[b]) + rec) + bhB[b];
                            float sp = (pmask >> sidx) & 1u ? 1.0f : 0.0f;
                            float ro = roB[b];
                            float bnew = (ro * hbv[a][b][r]) + ((1.0f - ro) * sp);
                            float B = 0.01f + (1.8f * bnew);
                            float mem = ((hm[a][b][r] * alpha) + (onem * h_in)) - (B * sp);
                            float s = (mem - B) > 0.f ? 1.f : 0.f;
                            hbv[a][b][r] = bnew; hm[a][b][r] = mem;
                            if (s > 0.5f) nmask |= (1u << sidx);
                        }
                    }
                }
            }
            pmask = nmask;

            // pack spikes: ballots -> holder lanes; gather rows 2p,2p+1 into
            // lane p<16; ONE contiguous 128B segment as 16 x 8B atomic stores.
            uint32_t wmine = 0;
            #pragma unroll
            for (int a = 0; a < 2; ++a) {
                #pragma unroll
                for (int r = 0; r < 4; ++r) {
                    unsigned long long bal0 = __ballot((nmask >> (a * 8 + r)) & 1u);
                    unsigned long long bal1 = __ballot((nmask >> (a * 8 + 4 + r)) & 1u);
                    if (col == a * 4 + r) {
                        wmine = (uint32_t)((bal0 >> (quad * 16)) & 0xFFFFull)
                              | ((uint32_t)((bal1 >> (quad * 16)) & 0xFFFFull) << 16);
                    }
                }
            }
            {
                uint32_t g0 = (uint32_t)__shfl((int)wmine, s0, 64);
                uint32_t g1 = (uint32_t)__shfl((int)wmine, s1, 64);
                if (lane < 16) {
                    uint64_t q = (uint64_t)g0 | ((uint64_t)g1 << 32);
                    uint64_t* qp = (uint64_t*)(wrP + (size_t)it * N_ + n0);
                    __hip_atomic_store(qp + (lane & 15), q,
                                       __ATOMIC_RELAXED, __HIP_MEMORY_SCOPE_AGENT);
                }
            }
        }

        if (is_o && active) {
            v4i oacc[2][4] = {};
            #pragma unroll
            for (int c = 0; c < 13; ++c) {
                uint32_t d0 = ldsA[col * AROW + c * 2 + dsel];
                uint32_t d1 = ldsA[(16 + col) * AROW + c * 2 + dsel];
                v4i a0 = unpack16((d0 >> dsh) & 0xFFFFu);
                v4i a1 = unpack16((d1 >> dsh) & 0xFFFFu);
                #pragma unroll
                for (int k = 0; k < 4; ++k) {
                    v4i bo = *(const v4i*)(Bl + (((c * 8) + k * 2 + 0) << 10) + (lane << 4));
                    oacc[0][k] = __builtin_amdgcn_mfma_i32_16x16x64_i8(a0, bo, oacc[0][k], 0, 0, 0);
                    oacc[1][k] = __builtin_amdgcn_mfma_i32_16x16x64_i8(a1, bo, oacc[1][k], 0, 0, 0);
                }
            }
            if (col < ONUM) {
                #pragma clang fp contract(off)
                const bool msk = (t - 1) >= TENC;
                #pragma unroll
                for (int a = 0; a < 2; ++a) {
                    #pragma unroll
                    for (int r = 0; r < 4; ++r) {
                        int64_t tot = ((int64_t)oacc[a][3][r] << 24)
                                    + ((int64_t)oacc[a][2][r] << 16)
                                    + ((int64_t)oacc[a][1][r] << 8)
                                    +  (int64_t)oacc[a][0][r];
                        float o_in = ((float)((double)tot * INV32)) + boO;
                        float osp_ = ospv[a][r];
                        float bnew = (roO * obb[a][r]) + ((1.0f - roO) * osp_);
                        float B = 0.01f + (1.8f * bnew);
                        float mem = ((om[a][r] * alpha) + (onem * o_in)) - (B * osp_);
                        float s = (mem - B) > 0.f ? 1.f : 0.f;
                        obb[a][r] = bnew; om[a][r] = mem; ospv[a][r] = s;
                        if (msk) cnt[a][r] += s;
                    }
                }
            }
        }

        if (t < TTOT) pod_barrier(flags, pod, l, epoch++);
    }

    // ---- write spike counts ----
    if (is_o && col < ONUM) {
        #pragma unroll
        for (int a = 0; a < 2; ++a)
            #pragma unroll
            for (int r = 0; r < 4; ++r) {
                int n = n0 + a * 16 + quad * 4 + r;
                out[(size_t)n * ONUM + col] = cnt[a][r];
            }
    }
}

// ---------------------------------------------------------------------------
extern "C" void kernel_launch(void* const* d_in, const int* in_sizes, int n_in,
                              void* d_out, int out_size, void* d_ws, size_t ws_size,
                              hipStream_t stream)
{
    const float* x      = (const float*)d_in[0];
    const float* Wi     = (const float*)d_in[1];
    const float* b_i2h  = (const float*)d_in[2];
    const float* Wh     = (const float*)d_in[3];
    const float* b_h2h  = (const float*)d_in[4];
    const float* Wo     = (const float*)d_in[5];
    const float* b_h2o  = (const float*)d_in[6];
    const float* tau_h  = (const float*)d_in[7];
    const float* tau_o  = (const float*)d_in[8];
    float* out = (float*)d_out;

    uintptr_t p = (uintptr_t)d_ws;
    auto alloc = [&](size_t bytes) -> void* {
        p = (p + 255) & ~(uintptr_t)255;
        void* r = (void*)p; p += bytes; return r;
    };
    uint32_t* sp0   = (uint32_t*)alloc((size_t)NTILE * N_ * 4);
    uint32_t* sp1   = (uint32_t*)alloc((size_t)NTILE * N_ * 4);
    float*    xt2   = (float*)alloc((size_t)TENC * N_ * IN_ * 4);
    uint32_t* flags = (uint32_t*)alloc((size_t)PODS * FSTR * 4);

    prep_kernel<<<1024, 256, 0, stream>>>(x, xt2, sp0, sp1, flags);

    (void)hipFuncSetAttribute((const void*)lsnn_persist,
                              hipFuncAttributeMaxDynamicSharedMemorySize, SMEM_TOT);
    lsnn_persist<<<NBLK, 512, SMEM_TOT, stream>>>(
        xt2, Wi, b_i2h, Wh, b_h2h, Wo, b_h2o, tau_h, tau_o,
        sp0, sp1, flags, out);
}